// Round 9
// baseline (896.444 us; speedup 1.0000x reference)
//
#include <hip/hip_runtime.h>

// Mesh2: out3 = [out1||out2] @ W_comb^T + b_comb ; out4 = mean(self+3nbrs) @ W_agg^T + b_agg
// R5-R8: LINEARITY SPLIT (Y = out2@W_agg^T in ws; gather in output space). 520us total:
//        gemm ~390us, gather ~125us. R8 BM=64 null -> NOT L2-B-bound; phase serialization
//        (stage|compute|store additive, ~16us/block vs 13us HBM share) is the limiter.
// R9: K-phased 2-buffer pipeline in gemm: 4 phases x 128 cols, 8.7KB LDS slices, 8 staged
//     VGPR/thread (fits the immovable 128-VGPR cap), raw s_barrier (loads in flight across
//     it), 1 barrier/phase. Y reuses the out2 A-fragments during phases 2-3.

typedef __bf16 bf16x8 __attribute__((ext_vector_type(8)));
typedef float f32x4 __attribute__((ext_vector_type(4)));

#define N_NODES 200000
#define BM 32
#define NTILES (N_NODES / BM)  // 6250
#define LDW 136                // 128 + 8 pad (bf16) -> 2-way banks on b128 (free, m136)
#define ROWC 520               // fallback only
#define ROWA 264               // fallback only
#define GRID_B 2048

__device__ __forceinline__ unsigned short f2bf(float x) {
  union { float f; unsigned int u; } v; v.f = x;
  return (unsigned short)((v.u + 0x7FFFu + ((v.u >> 16) & 1u)) >> 16);  // RNE
}

__device__ __forceinline__ void st_bf4(unsigned short* p, float4 f) {
  uint2 w;
  w.x = (unsigned int)f2bf(f.x) | ((unsigned int)f2bf(f.y) << 16);
  w.y = (unsigned int)f2bf(f.z) | ((unsigned int)f2bf(f.w) << 16);
  *reinterpret_cast<uint2*>(p) = w;
}

// Pack W (f32, row-major [O][K]) -> bf16 MFMA-B-fragment-linear layout:
// tile (nt,kt): lane l holds W[nt*16 + (l&15)][kt*32 + (l>>4)*8 + j] at P[tile*512 + l*8 + j].
__global__ void pack_w_kernel(const float* __restrict__ Wc,
                              const float* __restrict__ Wa,
                              unsigned short* __restrict__ Pc,
                              unsigned short* __restrict__ Pa) {
  int t = blockIdx.x * 256 + threadIdx.x;
  if (t >= (512 + 256) * 64) return;
  int lane = t & 63;
  int tile = t >> 6;
  const float* W;
  unsigned short* P;
  int K, kt_n;
  if (tile < 512) { W = Wc; P = Pc; K = 512; kt_n = 16; }
  else { tile -= 512; W = Wa; P = Pa; K = 256; kt_n = 8; }
  int nt = tile / kt_n;
  int kt = tile - nt * kt_n;
  int row = nt * 16 + (lane & 15);
  int k0 = kt * 32 + (lane >> 4) * 8;
  const float* src = W + (size_t)row * K + k0;
  unsigned short* dst = P + (size_t)tile * 512 + lane * 8;
#pragma unroll
  for (int j = 0; j < 8; ++j) dst[j] = f2bf(src[j]);
}

// ---------------- Kernel A: dense GEMM (out3 f32 + Y bf16), K-phased pipeline ----------------
__global__ __launch_bounds__(512, 2) void gemm_kernel(
    const float* __restrict__ out1, const float* __restrict__ out2,
    const unsigned short* __restrict__ Pc, const unsigned short* __restrict__ Pa,
    const float* __restrict__ b_comb,
    float* __restrict__ out3, unsigned short* __restrict__ Y) {
  __shared__ unsigned short lds[2][BM][LDW];  // 17.4 KB; reused by Y epilogue (needs 16.6 KB)

  const int tid = threadIdx.x;
  const int srow = tid >> 4, sc = tid & 15;  // stage role: row 0..31, 8-f32 chunk 0..15
  const int wave = tid >> 6, lane = tid & 63;
  const int l15 = lane & 15, l4 = lane >> 4;
  const long long node0 = (long long)blockIdx.x * BM;
  const int nt0 = wave * 4;

  float bcv[4];
#pragma unroll
  for (int n = 0; n < 4; ++n) bcv[n] = b_comb[wave * 64 + n * 16 + l15];

  f32x4 acc3[2][4], accY[2][4];
#pragma unroll
  for (int m = 0; m < 2; ++m)
#pragma unroll
    for (int n = 0; n < 4; ++n) {
      acc3[m][n] = (f32x4){0.f, 0.f, 0.f, 0.f};
      accY[m][n] = (f32x4){0.f, 0.f, 0.f, 0.f};
    }

  // staged regs for ONE 128-col phase: 2 x float4 = 8 VGPR
  float4 sA, sB;
  auto ldphase = [&](int p) {
    const float* s = (p < 2 ? out1 : out2) + (node0 + srow) * 256 + (p & 1) * 128 + sc * 8;
    sA = *reinterpret_cast<const float4*>(s);
    sB = *reinterpret_cast<const float4*>(s + 4);
  };

  ldphase(0);

#pragma unroll
  for (int p = 0; p < 4; ++p) {
    // convert staged(p) -> lds[p&1]  (compiler inserts the vmcnt wait on sA/sB here)
    st_bf4(&lds[p & 1][srow][sc * 8], sA);
    st_bf4(&lds[p & 1][srow][sc * 8 + 4], sB);
    // issue loads for p+1 NOW; raw barrier below does not drain vmcnt
    if (p < 3) ldphase(p + 1);
    asm volatile("s_waitcnt lgkmcnt(0)" ::: "memory");  // my ds_writes visible
    __builtin_amdgcn_s_barrier();                       // buf[p&1] ready block-wide

    // MFMA over this 128-col slice (4 kt of 32)
#pragma unroll
    for (int kt = 0; kt < 4; ++kt) {
      bf16x8 a0 = *reinterpret_cast<const bf16x8*>(&lds[p & 1][l15][kt * 32 + l4 * 8]);
      bf16x8 a1 = *reinterpret_cast<const bf16x8*>(&lds[p & 1][l15 + 16][kt * 32 + l4 * 8]);
#pragma unroll
      for (int n = 0; n < 4; ++n) {
        bf16x8 b =
            *reinterpret_cast<const bf16x8*>(Pc + ((size_t)(nt0 + n) * 16 + p * 4 + kt) * 512 + lane * 8);
        acc3[0][n] = __builtin_amdgcn_mfma_f32_16x16x32_bf16(a0, b, acc3[0][n], 0, 0, 0);
        acc3[1][n] = __builtin_amdgcn_mfma_f32_16x16x32_bf16(a1, b, acc3[1][n], 0, 0, 0);
      }
      if (p >= 2) {  // Y = out2 @ Wa^T reuses the same A-fragments
#pragma unroll
        for (int n = 0; n < 4; ++n) {
          bf16x8 b =
              *reinterpret_cast<const bf16x8*>(Pa + ((size_t)(nt0 + n) * 8 + (p - 2) * 4 + kt) * 512 + lane * 8);
          accY[0][n] = __builtin_amdgcn_mfma_f32_16x16x32_bf16(a0, b, accY[0][n], 0, 0, 0);
          accY[1][n] = __builtin_amdgcn_mfma_f32_16x16x32_bf16(a1, b, accY[1][n], 0, 0, 0);
        }
      }
    }
  }

  // ---- out3 store (frees acc3 before the Y epilogue) ----
  {
    float* o3 = out3 + node0 * 512 + wave * 64 + l15;
#pragma unroll
    for (int m = 0; m < 2; ++m)
#pragma unroll
      for (int r = 0; r < 4; ++r) {
        float* pp = o3 + (long long)(m * 16 + l4 * 4 + r) * 512;
#pragma unroll
        for (int n = 0; n < 4; ++n) pp[n * 16] = acc3[m][n][r] + bcv[n];
      }
  }

  // ---- Y epilogue: 2 chunks of 16 rows through LDS -> coalesced uint4 stores ----
  unsigned short* yl = &lds[0][0][0];  // flat 17408 B >= 16*520*2
#pragma unroll
  for (int ch = 0; ch < 2; ++ch) {
    __syncthreads();  // prior LDS reads (phase MFMA / previous readout) complete
#pragma unroll
    for (int r = 0; r < 4; ++r) {
      const int rl = l4 * 4 + r;  // chunk-local row 0..15
#pragma unroll
      for (int n = 0; n < 4; ++n)
        yl[rl * 520 + wave * 64 + n * 16 + l15] = f2bf(accY[ch][n][r]);
    }
    __syncthreads();
#pragma unroll
    for (int q = 0; q < 2; ++q) {
      const int idx = q * 512 + tid;  // 0..1023 = 16 rows x 64 chunks
      const int row = idx >> 6, c = idx & 63;
      *reinterpret_cast<uint4*>(Y + (node0 + ch * 16 + row) * 512 + c * 8) =
          *reinterpret_cast<const uint4*>(yl + row * 520 + c * 8);
    }
  }
}

// ---------------- Kernel B: out4 = 0.25*(Y[n]+Y[i0]+Y[i1]+Y[i2]) + b_agg ----------------
__device__ __forceinline__ float bf_lo(unsigned u) {
  union { unsigned x; float f; } c; c.x = u << 16; return c.f;
}
__device__ __forceinline__ float bf_hi(unsigned u) {
  union { unsigned x; float f; } c; c.x = u & 0xFFFF0000u; return c.f;
}

__global__ __launch_bounds__(256) void gather_kernel(
    const unsigned short* __restrict__ Y, const int* __restrict__ nbr,
    const float* __restrict__ b_agg, float* __restrict__ out4) {
  const int lane = threadIdx.x & 63;
  const int wid = (blockIdx.x * 256 + threadIdx.x) >> 6;
  const int nwaves = (GRID_B * 256) >> 6;

  float ba[8];
  const float* bp = b_agg + lane * 8;
#pragma unroll
  for (int j = 0; j < 8; ++j) ba[j] = bp[j];

  for (int n = wid; n < N_NODES; n += nwaves) {
    int i0 = nbr[3 * n + 0];
    int i1 = nbr[3 * n + 1];
    int i2 = nbr[3 * n + 2];
    i0 = i0 < 0 ? 0 : (i0 >= N_NODES ? N_NODES - 1 : i0);
    i1 = i1 < 0 ? 0 : (i1 >= N_NODES ? N_NODES - 1 : i1);
    i2 = i2 < 0 ? 0 : (i2 >= N_NODES ? N_NODES - 1 : i2);

    const uint4 a  = *reinterpret_cast<const uint4*>(Y + (size_t)n  * 512 + lane * 8);
    const uint4 b0 = *reinterpret_cast<const uint4*>(Y + (size_t)i0 * 512 + lane * 8);
    const uint4 b1 = *reinterpret_cast<const uint4*>(Y + (size_t)i1 * 512 + lane * 8);
    const uint4 b2 = *reinterpret_cast<const uint4*>(Y + (size_t)i2 * 512 + lane * 8);

    const unsigned wa[4] = {a.x, a.y, a.z, a.w};
    const unsigned w0[4] = {b0.x, b0.y, b0.z, b0.w};
    const unsigned w1[4] = {b1.x, b1.y, b1.z, b1.w};
    const unsigned w2[4] = {b2.x, b2.y, b2.z, b2.w};
    float s[8];
#pragma unroll
    for (int w = 0; w < 4; ++w) {
      s[2 * w]     = bf_lo(wa[w]) + bf_lo(w0[w]) + bf_lo(w1[w]) + bf_lo(w2[w]);
      s[2 * w + 1] = bf_hi(wa[w]) + bf_hi(w0[w]) + bf_hi(w1[w]) + bf_hi(w2[w]);
    }
    f32x4 o0 = {s[0] * 0.25f + ba[0], s[1] * 0.25f + ba[1],
                s[2] * 0.25f + ba[2], s[3] * 0.25f + ba[3]};
    f32x4 o1 = {s[4] * 0.25f + ba[4], s[5] * 0.25f + ba[5],
                s[6] * 0.25f + ba[6], s[7] * 0.25f + ba[7]};
    f32x4* op = reinterpret_cast<f32x4*>(out4 + (size_t)n * 512 + lane * 8);
    __builtin_nontemporal_store(o0, op);
    __builtin_nontemporal_store(o1, op + 1);
  }
}

// ---------------- Fallback (R2-style, known-good) if ws too small for Y ----------------
__global__ __launch_bounds__(512, 4) void mesh_fused_fallback(
    const float* __restrict__ out1, const float* __restrict__ out2,
    const int* __restrict__ nbr,
    const unsigned short* __restrict__ Pc, const unsigned short* __restrict__ Pa,
    const float* __restrict__ b_comb, const float* __restrict__ b_agg,
    float* __restrict__ outp) {
  __shared__ unsigned short Ac[32 * ROWC];
  __shared__ unsigned short Aagg[32 * ROWA];
  const int tid = threadIdx.x;
  const long long node0 = (long long)blockIdx.x * 32;
  {
    const int ln = tid >> 4, c16 = tid & 15;
    const long long gn = node0 + ln;
    long long i0 = nbr[3 * gn + 0], i1 = nbr[3 * gn + 1], i2 = nbr[3 * gn + 2];
    i0 = i0 < 0 ? 0 : (i0 >= N_NODES ? N_NODES - 1 : i0);
    i1 = i1 < 0 ? 0 : (i1 >= N_NODES ? N_NODES - 1 : i1);
    i2 = i2 < 0 ? 0 : (i2 >= N_NODES ? N_NODES - 1 : i2);
    const float4* r1 = reinterpret_cast<const float4*>(out1 + gn * 256);
    const float4* r2 = reinterpret_cast<const float4*>(out2 + gn * 256);
    const float4* g0 = reinterpret_cast<const float4*>(out2 + i0 * 256);
    const float4* g1 = reinterpret_cast<const float4*>(out2 + i1 * 256);
    const float4* g2 = reinterpret_cast<const float4*>(out2 + i2 * 256);
#pragma unroll
    for (int r = 0; r < 4; ++r) {
      const int c = c16 + 16 * r;
      float4 f1 = r1[c], f2 = r2[c], n0 = g0[c], n1 = g1[c], n2 = g2[c];
      float4 ag;
      ag.x = (f2.x + n0.x + n1.x + n2.x) * 0.25f;
      ag.y = (f2.y + n0.y + n1.y + n2.y) * 0.25f;
      ag.z = (f2.z + n0.z + n1.z + n2.z) * 0.25f;
      ag.w = (f2.w + n0.w + n1.w + n2.w) * 0.25f;
      st_bf4(&Ac[ln * ROWC + c * 4], f1);
      st_bf4(&Ac[ln * ROWC + 256 + c * 4], f2);
      st_bf4(&Aagg[ln * ROWA + c * 4], ag);
    }
  }
  __syncthreads();
  const int wave = tid >> 6, lane = tid & 63;
  const int l15 = lane & 15, l4 = lane >> 4;
  const int nt0 = wave * 4;
  float* o3 = outp;
  float* o4 = outp + (size_t)N_NODES * 512;
  {
    f32x4 acc[2][4];
#pragma unroll
    for (int m = 0; m < 2; ++m)
#pragma unroll
      for (int n = 0; n < 4; ++n) acc[m][n] = (f32x4){0.f, 0.f, 0.f, 0.f};
    const unsigned short* pc = Pc + (size_t)nt0 * 16 * 512 + lane * 8;
    const unsigned short* ab = &Ac[(size_t)l15 * ROWC + l4 * 8];
#pragma unroll
    for (int kt = 0; kt < 16; ++kt) {
      bf16x8 a0 = *reinterpret_cast<const bf16x8*>(ab + kt * 32);
      bf16x8 a1 = *reinterpret_cast<const bf16x8*>(ab + 16 * ROWC + kt * 32);
#pragma unroll
      for (int n = 0; n < 4; ++n) {
        bf16x8 b = *reinterpret_cast<const bf16x8*>(pc + ((size_t)n * 16 + kt) * 512);
        acc[0][n] = __builtin_amdgcn_mfma_f32_16x16x32_bf16(a0, b, acc[0][n], 0, 0, 0);
        acc[1][n] = __builtin_amdgcn_mfma_f32_16x16x32_bf16(a1, b, acc[1][n], 0, 0, 0);
      }
    }
#pragma unroll
    for (int m = 0; m < 2; ++m)
#pragma unroll
      for (int r = 0; r < 4; ++r)
#pragma unroll
        for (int n = 0; n < 4; ++n) {
          const int col = wave * 64 + n * 16 + l15;
          o3[(node0 + m * 16 + l4 * 4 + r) * 512 + col] = acc[m][n][r] + b_comb[col];
        }
  }
  {
    f32x4 acc[2][4];
#pragma unroll
    for (int m = 0; m < 2; ++m)
#pragma unroll
      for (int n = 0; n < 4; ++n) acc[m][n] = (f32x4){0.f, 0.f, 0.f, 0.f};
    const unsigned short* pa = Pa + (size_t)nt0 * 8 * 512 + lane * 8;
    const unsigned short* ab = &Aagg[(size_t)l15 * ROWA + l4 * 8];
#pragma unroll
    for (int kt = 0; kt < 8; ++kt) {
      bf16x8 a0 = *reinterpret_cast<const bf16x8*>(ab + kt * 32);
      bf16x8 a1 = *reinterpret_cast<const bf16x8*>(ab + 16 * ROWA + kt * 32);
#pragma unroll
      for (int n = 0; n < 4; ++n) {
        bf16x8 b = *reinterpret_cast<const bf16x8*>(pa + ((size_t)n * 8 + kt) * 512);
        acc[0][n] = __builtin_amdgcn_mfma_f32_16x16x32_bf16(a0, b, acc[0][n], 0, 0, 0);
        acc[1][n] = __builtin_amdgcn_mfma_f32_16x16x32_bf16(a1, b, acc[1][n], 0, 0, 0);
      }
    }
#pragma unroll
    for (int m = 0; m < 2; ++m)
#pragma unroll
      for (int r = 0; r < 4; ++r)
#pragma unroll
        for (int n = 0; n < 4; ++n) {
          const int col = wave * 64 + n * 16 + l15;
          o4[(node0 + m * 16 + l4 * 4 + r) * 512 + col] = acc[m][n][r] + b_agg[col];
        }
  }
}

extern "C" void kernel_launch(void* const* d_in, const int* in_sizes, int n_in,
                              void* d_out, int out_size, void* d_ws, size_t ws_size,
                              hipStream_t stream) {
  const float* out1 = (const float*)d_in[0];
  const float* out2 = (const float*)d_in[1];
  const int* nbr = (const int*)d_in[2];  // harness pushes integers as int32
  const float* Wc = (const float*)d_in[3];
  const float* bc = (const float*)d_in[4];
  const float* Wa = (const float*)d_in[5];
  const float* ba = (const float*)d_in[6];

  const size_t yElems = (size_t)N_NODES * 512;     // bf16 Y: 204.8 MB
  const size_t packElems = 512 * 512 + 512 * 256;  // 768 KB
  const size_t need = (yElems + packElems) * 2;

  if (ws_size >= need) {
    unsigned short* Yw = (unsigned short*)d_ws;
    unsigned short* Pc = Yw + yElems;
    unsigned short* Pa = Pc + 512 * 512;
    pack_w_kernel<<<192, 256, 0, stream>>>(Wc, Wa, Pc, Pa);
    gemm_kernel<<<NTILES, 512, 0, stream>>>(out1, out2, Pc, Pa, bc, (float*)d_out, Yw);
    gather_kernel<<<GRID_B, 256, 0, stream>>>(Yw, nbr, ba,
                                              (float*)d_out + (size_t)N_NODES * 512);
  } else {
    unsigned short* Pc = (unsigned short*)d_ws;
    unsigned short* Pa = Pc + 512 * 512;
    pack_w_kernel<<<192, 256, 0, stream>>>(Wc, Wa, Pc, Pa);
    mesh_fused_fallback<<<N_NODES / 32, 512, 0, stream>>>(out1, out2, nbr, Pc, Pa, bc, ba,
                                                          (float*)d_out);
  }
}